// Round 18
// baseline (1818.305 us; speedup 1.0000x reference)
//
#include <hip/hip_runtime.h>
#include <math.h>

#define Bx 16
#define Cx 64
#define Hx 128
#define Wx 128
#define HWx (Hx * Wx)

#define TW 32
#define TH 8
#define CCH 8
#define HALO_W (TW + 2)
#define HALO_H (TH + 2)
#define CPLANE (HALO_H * HALO_W)          // 340
#define CHUNK_ELEMS (CCH * CPLANE)        // 2720
#define NCHUNK (Cx / CCH)                 // 8

// workspace layout (float/u32 offsets) — R13/R17 layout (gpack8)
#define WS_CWB   0                         // 1x1 B-fragments bf16: 2048 u32
#define WS_GPACK 2048                      // gpack8[c*72 + k*8 + rg]  4608  (rg=r*2+g)
#define WS_KERN  6656                      // per-b [c*36+k*4+g]       16*2304
#define WS_ATT   43520                     // per-b [c*4+r]            16*256

typedef short bf16x8 __attribute__((ext_vector_type(8)));
typedef float f32x4  __attribute__((ext_vector_type(4)));
typedef float f32x2  __attribute__((ext_vector_type(2)));
typedef unsigned int u32x4 __attribute__((ext_vector_type(4)));

__device__ __host__ inline unsigned rne_bf16(float f) {
    union { float f; unsigned u; } v; v.f = f;
    return (v.u + 0x7fffu + ((v.u >> 16) & 1u)) >> 16;
}

// rbuf row swizzle: 4 slots of 16B per 64B pixel row (R13-validated)
#define RSWZ(p) ((((p) & 3) ^ (((p) >> 2) & 3)))

// ---------------- prep: hypernetwork + weight repacking (R17 verbatim) ----------------
__global__ __launch_bounds__(256)
void da_prep(const float* __restrict__ x_deg,
             const float* __restrict__ kw1,
             const float* __restrict__ kw2,
             const float* __restrict__ convw,
             const float* __restrict__ ca_w1,
             const float* __restrict__ ca_w2,
             const float* __restrict__ g1w,
             const float* __restrict__ g2w,
             float* __restrict__ ws)
{
    const int b = blockIdx.x;
    const int tid = threadIdx.x;
    unsigned int* wsu = (unsigned int*)ws;

    if (b == Bx) {
        // 1x1 weights as MFMA B-fragments, bf16 RNE (R12-validated layout).
        for (int i = tid; i < 2048; i += 256) {
            const int t    = i >> 8;
            const int rem  = i & 255;
            const int lane = rem >> 2;
            const int w    = rem & 3;
            const int nt = t >> 1, ks = t & 1;
            const int o = nt * 16 + (lane & 15);
            const int c = ks * 32 + ((lane >> 4) << 3) + w * 2;
            const unsigned lo = rne_bf16(convw[o * 64 + c]);
            const unsigned hi = rne_bf16(convw[o * 64 + c + 1]);
            wsu[WS_CWB + i] = lo | (hi << 16);
        }
        // guide weights packed [c][k][8rg]: rg adjacent -> float2 pairs
        for (int i = tid; i < 4608; i += 256) {
            const int c = i / 72;
            const int rem = i - c * 72;
            const int k  = rem >> 3;
            const int rg = rem & 7;
            const int r = rg >> 1;
            const int g = rg & 1;
            const float* src = g ? g2w : g1w;
            ws[WS_GPACK + i] = src[(r * Cx + c) * 9 + k];
        }
        return;
    }

    __shared__ float h1[16];
    __shared__ float a1[16];
    if (tid < 32) {
        const int j = tid & 15;
        const float* wsrc = (tid < 16) ? (kw1 + j * Cx) : (ca_w1 + j * Cx);
        float acc = 0.f;
        #pragma unroll 8
        for (int c = 0; c < Cx; ++c) acc = fmaf(x_deg[b * Cx + c], wsrc[c], acc);
        acc = acc > 0.f ? acc : 0.1f * acc;               // leaky_relu 0.1
        if (tid < 16) h1[j] = acc; else a1[j] = acc;
    }
    __syncthreads();

    for (int o4 = tid; o4 < 4 * 576; o4 += 256) {
        const int g = o4 / 576;
        const int o = o4 - g * 576;
        float acc = 0.f;
        #pragma unroll
        for (int i = 0; i < 4; ++i)
            acc = fmaf(h1[g * 4 + i], kw2[(g * 576 + o) * 4 + i], acc);
        const int c = o / 9;
        const int k = o - c * 9;
        ws[WS_KERN + b * 2304 + c * 36 + k * 4 + g] = acc;
    }
    {
        const int r = tid >> 6;
        const int c = tid & 63;
        float acc = 0.f;
        #pragma unroll
        for (int i = 0; i < 4; ++i)
            acc = fmaf(a1[r * 4 + i], ca_w2[(r * Cx + c) * 4 + i], acc);
        ws[WS_ATT + b * 256 + c * 4 + r] = 1.f / (1.f + expf(-acc));
    }
}

// ---------------- main: R17 + pass-1-only staging pipeline ----------------
// Spill-law audit: every spilling round (R2/R4/R7/R8) interleaved staging
// with the y[64]/acc body. Pass-1's live set is only ga[8] — pipelining it
// was never tested in isolation. This round: sx double-buffer, pass-1 does
// {prefetch next (11 named scalars) -> compute current -> write prefetch ->
// ONE barrier}. Pass-2 (acc AGPRs live) stays strictly phase-separated
// (R17 verbatim). Math/argmax bit-identical to R17 (absmax 0.015625).
__global__ __launch_bounds__(256, 2)
void da_main(const float* __restrict__ x0,
             const float* __restrict__ ws,
             const float* __restrict__ g1b,
             const float* __restrict__ g2b,
             const float* __restrict__ convb,
             float* __restrict__ out)
{
    const int b  = blockIdx.z;
    const int h0 = blockIdx.y * TH;
    const int w0 = blockIdx.x * TW;
    const int tid = threadIdx.x;
    const int tx = tid & (TW - 1);
    const int ty = tid >> 5;
    const int lane = tid & 63;
    const int wave = tid >> 6;

    // swts: pass1 = gpack8 [c][k][8] (4608 fl); pass2 = skern[0,2304)+satt[2304,2560)
    __shared__ __align__(16) float swts[4608];            // 18,432 B
    // pool: sx[2][2720] @0 (21,760 B) | rbuf @21760 (16,384 B)
    // after GEMM: pool dead -> sy transpose (4 x 1088 fl)
    __shared__ __align__(16) char pool[38144];
    char*  rbuf = pool + 21760;
    // total 56,576 B -> 2 blocks/CU

    const float* xb  = x0 + (size_t)b * Cx * HWx;
    const float* kws = ws + WS_KERN + b * 2304;
    const float* aws = ws + WS_ATT  + b * 256;
    const unsigned int* wsu = (const unsigned int*)ws;

    // --- per-thread staging offsets, computed ONCE (named ints, no array) ---
    int o0, o1, o2, o3, o4, o5, o6, o7, o8, o9, o10;
    unsigned vmask = 0u;
#define MKOFF(i, oname)                                                        \
    do {                                                                       \
        const int e   = tid + (i) * 256;                                       \
        const int cc  = e / CPLANE;                                            \
        const int rem = e - cc * CPLANE;                                       \
        const int row = rem / HALO_W;                                          \
        const int col = rem - row * HALO_W;                                    \
        const int gh  = h0 - 1 + row;                                          \
        const int gw  = w0 - 1 + col;                                          \
        oname = cc * HWx + gh * Wx + gw;                                       \
        if (e < CHUNK_ELEMS && (unsigned)gh < Hx && (unsigned)gw < Wx)         \
            vmask |= (1u << (i));                                              \
    } while (0)
    MKOFF(0, o0);  MKOFF(1, o1);  MKOFF(2, o2);  MKOFF(3, o3);
    MKOFF(4, o4);  MKOFF(5, o5);  MKOFF(6, o6);  MKOFF(7, o7);
    MKOFF(8, o8);  MKOFF(9, o9);  MKOFF(10, o10);
#undef MKOFF

    // batched staging into a given buffer: issue all loads, then all writes
#define STAGE_CHUNK_TO(ch, sxd)                                                \
    do {                                                                       \
        const float* src = xb + (size_t)(ch) * CCH * HWx;                      \
        float v0 = 0.f, v1 = 0.f, v2 = 0.f, v3 = 0.f, v4 = 0.f, v5 = 0.f;     \
        float v6 = 0.f, v7 = 0.f, v8 = 0.f, v9 = 0.f, v10 = 0.f;              \
        if (vmask & 1u)      v0  = src[o0];                                    \
        if (vmask & 2u)      v1  = src[o1];                                    \
        if (vmask & 4u)      v2  = src[o2];                                    \
        if (vmask & 8u)      v3  = src[o3];                                    \
        if (vmask & 16u)     v4  = src[o4];                                    \
        if (vmask & 32u)     v5  = src[o5];                                    \
        if (vmask & 64u)     v6  = src[o6];                                    \
        if (vmask & 128u)    v7  = src[o7];                                    \
        if (vmask & 256u)    v8  = src[o8];                                    \
        if (vmask & 512u)    v9  = src[o9];                                    \
        if (vmask & 1024u)   v10 = src[o10];                                   \
        (sxd)[tid]          = v0;   (sxd)[tid + 256]  = v1;                    \
        (sxd)[tid + 512]    = v2;   (sxd)[tid + 768]  = v3;                    \
        (sxd)[tid + 1024]   = v4;   (sxd)[tid + 1280] = v5;                    \
        (sxd)[tid + 1536]   = v6;   (sxd)[tid + 1792] = v7;                    \
        (sxd)[tid + 2048]   = v8;   (sxd)[tid + 2304] = v9;                    \
        if (tid < CHUNK_ELEMS - 2560) (sxd)[tid + 2560] = v10;                 \
    } while (0)

    // --- prologue: gpack8 (1152 float4) batched into LDS + chunk 0 into buf 0 ---
    {
        const float4* s4 = (const float4*)(ws + WS_GPACK);
        float4* d4 = (float4*)swts;
        const float4 g0 = s4[tid], g1 = s4[tid + 256];
        const float4 g2 = s4[tid + 512], g3 = s4[tid + 768];
        float4 g4 = (float4){0.f, 0.f, 0.f, 0.f};
        if (tid < 128) g4 = s4[tid + 1024];
        d4[tid] = g0; d4[tid + 256] = g1; d4[tid + 512] = g2; d4[tid + 768] = g3;
        if (tid < 128) d4[tid + 1024] = g4;
    }
    STAGE_CHUNK_TO(0, (float*)pool);
    __syncthreads();

    // ================= PASS 1: pipelined guide convs -> argmax =================
    float ga[8];
    #pragma unroll
    for (int r = 0; r < 4; ++r) { ga[r] = g1b[r]; ga[4 + r] = g2b[r]; }

    #pragma unroll 1
    for (int ch = 0; ch < NCHUNK; ++ch) {
        const int buf = ch & 1;
        const float* sxc = (const float*)pool + buf * 2720;

        // prefetch next chunk into named scalars (no array -> no alloca)
        float p0 = 0.f, p1 = 0.f, p2 = 0.f, p3 = 0.f, p4 = 0.f, p5 = 0.f;
        float p6 = 0.f, p7 = 0.f, p8 = 0.f, p9 = 0.f, p10 = 0.f;
        if (ch < NCHUNK - 1) {
            const float* src = xb + (size_t)(ch + 1) * CCH * HWx;
            if (vmask & 1u)    p0  = src[o0];
            if (vmask & 2u)    p1  = src[o1];
            if (vmask & 4u)    p2  = src[o2];
            if (vmask & 8u)    p3  = src[o3];
            if (vmask & 16u)   p4  = src[o4];
            if (vmask & 32u)   p5  = src[o5];
            if (vmask & 64u)   p6  = src[o6];
            if (vmask & 128u)  p7  = src[o7];
            if (vmask & 256u)  p8  = src[o8];
            if (vmask & 512u)  p9  = src[o9];
            if (vmask & 1024u) p10 = src[o10];
        }

        float pg[8] = {0.f, 0.f, 0.f, 0.f, 0.f, 0.f, 0.f, 0.f};
        #pragma unroll
        for (int cc = 0; cc < CCH; ++cc) {
            const int c = ch * CCH + cc;
            float n[9];
            #pragma unroll
            for (int kh = 0; kh < 3; ++kh)
                #pragma unroll
                for (int kw = 0; kw < 3; ++kw)
                    n[kh * 3 + kw] = sxc[cc * CPLANE + (ty + kh) * HALO_W + (tx + kw)];
            const float4* wp = (const float4*)(swts + c * 72);
            // packed pairs (rg0,rg1)(rg2,rg3)(rg4,rg5)(rg6,rg7); per-component
            // chains k-ascending — bit-identical to R17 (argmax-safe).
            f32x2 a0 = {0.f, 0.f}, a1 = {0.f, 0.f}, a2 = {0.f, 0.f}, a3 = {0.f, 0.f};
            #pragma unroll
            for (int k = 0; k < 9; ++k) {
                const float4 q0 = wp[k * 2];
                const float4 q1 = wp[k * 2 + 1];
                const f32x2 nn = {n[k], n[k]};
                a0 = __builtin_elementwise_fma(nn, (f32x2){q0.x, q0.y}, a0);
                a1 = __builtin_elementwise_fma(nn, (f32x2){q0.z, q0.w}, a1);
                a2 = __builtin_elementwise_fma(nn, (f32x2){q1.x, q1.y}, a2);
                a3 = __builtin_elementwise_fma(nn, (f32x2){q1.z, q1.w}, a3);
            }
            pg[0] += a0.x; pg[4] += a0.y;
            pg[1] += a1.x; pg[5] += a1.y;
            pg[2] += a2.x; pg[6] += a2.y;
            pg[3] += a3.x; pg[7] += a3.y;
        }
        #pragma unroll
        for (int i = 0; i < 8; ++i) ga[i] += pg[i];

        // write prefetched chunk into the other buffer, then one barrier
        if (ch < NCHUNK - 1) {
            float* sxn = (float*)pool + (buf ^ 1) * 2720;
            sxn[tid]          = p0;   sxn[tid + 256]  = p1;
            sxn[tid + 512]    = p2;   sxn[tid + 768]  = p3;
            sxn[tid + 1024]   = p4;   sxn[tid + 1280] = p5;
            sxn[tid + 1536]   = p6;   sxn[tid + 1792] = p7;
            sxn[tid + 2048]   = p8;   sxn[tid + 2304] = p9;
            if (tid < CHUNK_ELEMS - 2560) sxn[tid + 2560] = p10;
        }
        __syncthreads();
    }

    int r1 = 0, r2 = 0;
    {
        float m = ga[0];
        #pragma unroll
        for (int r = 1; r < 4; ++r) if (ga[r] > m) { m = ga[r]; r1 = r; }   // first-max ties
        float m2 = ga[4];
        #pragma unroll
        for (int r = 1; r < 4; ++r) if (ga[4 + r] > m2) { m2 = ga[4 + r]; r2 = r; }
    }

    // --- pass transition: overlay skern+satt into swts (batched, R12) ---
    // (pass-1 loop ended with a barrier; all gpack reads complete)
    {
        const float4* k4 = (const float4*)kws;
        const float4 k0 = k4[tid], k1 = k4[tid + 256];
        const float kt = kws[2048 + tid];
        const float at = aws[tid];
        float4* kd4 = (float4*)swts;                  // skern at 0
        kd4[tid] = k0; kd4[tid + 256] = k1;
        swts[2048 + tid] = kt;                        // skern tail
        swts[2304 + tid] = at;                        // satt
    }
    // visibility: pass-2 loop-top barrier

    // ================= PASS 2: depthwise -> bf16 rbuf, K-split GEMM (R17 verbatim) =================
    float* sx = (float*)pool;      // pass-2 uses buffer 0 only

#define DW_CHUNK(ch)                                                           \
    do {                                                                       \
        unsigned int us[4] = {0u, 0u, 0u, 0u};                                 \
        _Pragma("unroll")                                                      \
        for (int cc = 0; cc < CCH; ++cc) {                                     \
            const int c = (ch) * CCH + cc;                                     \
            float n[9];                                                        \
            _Pragma("unroll")                                                  \
            for (int kh = 0; kh < 3; ++kh)                                     \
                _Pragma("unroll")                                              \
                for (int kw = 0; kw < 3; ++kw)                                 \
                    n[kh * 3 + kw] = sx[cc * CPLANE + (ty + kh) * HALO_W + (tx + kw)]; \
            float dw = 0.f;                                                    \
            _Pragma("unroll")                                                  \
            for (int k = 0; k < 9; ++k)                                        \
                dw = fmaf(n[k], swts[c * 36 + k * 4 + r1], dw);                \
            const float routed = dw > 0.f ? dw : 0.1f * dw;                    \
            us[cc >> 1] |= rne_bf16(routed) << ((cc & 1) * 16);                \
        }                                                                      \
        const int byteoff = wave * 4096 + lane * 64 +                          \
                            ((((ch) & 3) ^ RSWZ(lane)) << 4);                  \
        *(u32x4*)(rbuf + byteoff) = (u32x4){us[0], us[1], us[2], us[3]};       \
    } while (0)

    f32x4 acc[4][4];

#define GEMM_HALF(ks)                                                          \
    do {                                                                       \
        const bf16x8* bglob = (const bf16x8*)(wsu + WS_CWB);                   \
        bf16x8 av[4];                                                          \
        _Pragma("unroll")                                                      \
        for (int mt = 0; mt < 4; ++mt) {                                       \
            const int pix = mt * 16 + (lane & 15);                             \
            const int sk = lane >> 4;                                          \
            av[mt] = *(const bf16x8*)(rbuf + wave * 4096 + pix * 64 +          \
                                      ((sk ^ RSWZ(pix)) << 4));                \
        }                                                                      \
        bf16x8 bv[4];                                                          \
        _Pragma("unroll")                                                      \
        for (int nt = 0; nt < 4; ++nt)                                         \
            bv[nt] = bglob[(nt * 2 + (ks)) * 64 + lane];                       \
        _Pragma("unroll")                                                      \
        for (int mt = 0; mt < 4; ++mt)                                         \
            _Pragma("unroll")                                                  \
            for (int nt = 0; nt < 4; ++nt)                                     \
                acc[mt][nt] = __builtin_amdgcn_mfma_f32_16x16x32_bf16(         \
                    av[mt], bv[nt], acc[mt][nt], 0, 0, 0);                     \
    } while (0)

    #pragma unroll 1
    for (int ch = 0; ch < 4; ++ch) {
        __syncthreads();
        STAGE_CHUNK_TO(ch, sx);
        __syncthreads();
        DW_CHUNK(ch);
    }
    #pragma unroll
    for (int mt = 0; mt < 4; ++mt)
        #pragma unroll
        for (int nt = 0; nt < 4; ++nt)
            acc[mt][nt] = (f32x4){0.f, 0.f, 0.f, 0.f};
    GEMM_HALF(0);          // same-wave rbuf write->read: in-order DS

    #pragma unroll 1
    for (int ch = 4; ch < 8; ++ch) {
        __syncthreads();
        STAGE_CHUNK_TO(ch, sx);
        __syncthreads();
        DW_CHUNK(ch);
    }
    GEMM_HALF(1);

    __syncthreads();       // all sx/rbuf reads done: pool becomes sy

    // --- epilogue per nt-group: padded transpose + store (R13-validated) ---
    const int hh = h0 + ty;
    const int ww = w0 + tx;
    float* op = out + (size_t)b * Cx * HWx + hh * Wx + ww;
    const float* xp = xb + hh * Wx + ww;
    float* syw = (float*)pool + wave * 1088;
    #pragma unroll
    for (int nt = 0; nt < 4; ++nt) {
        #pragma unroll
        for (int mt = 0; mt < 4; ++mt)
            #pragma unroll
            for (int q = 0; q < 4; ++q)
                syw[(mt * 16 + (lane >> 4) * 4 + q) * 17 + (lane & 15)] = acc[mt][nt][q];
        #pragma unroll
        for (int t = 0; t < 16; ++t) {
            const int o = nt * 16 + t;
            const float v = syw[lane * 17 + t] + convb[o]
                          + xp[(size_t)o * HWx] * swts[2304 + o * 4 + r2];
            op[(size_t)o * HWx] = v;
        }
    }
}

extern "C" void kernel_launch(void* const* d_in, const int* in_sizes, int n_in,
                              void* d_out, int out_size, void* d_ws, size_t ws_size,
                              hipStream_t stream) {
    const float* x0     = (const float*)d_in[0];
    const float* x_deg  = (const float*)d_in[1];
    const float* kw1    = (const float*)d_in[2];
    const float* kw2    = (const float*)d_in[3];
    const float* convw  = (const float*)d_in[4];
    const float* convb  = (const float*)d_in[5];
    const float* ca_w1  = (const float*)d_in[6];
    const float* ca_w2  = (const float*)d_in[7];
    const float* g1w    = (const float*)d_in[8];
    const float* g1b    = (const float*)d_in[9];
    const float* g2w    = (const float*)d_in[10];
    const float* g2b    = (const float*)d_in[11];
    float* outp = (float*)d_out;
    float* wsf  = (float*)d_ws;

    da_prep<<<Bx + 1, 256, 0, stream>>>(x_deg, kw1, kw2, convw, ca_w1, ca_w2,
                                        g1w, g2w, wsf);

    dim3 grid(Wx / TW, Hx / TH, Bx);   // 4 x 16 x 16 = 1024 blocks
    da_main<<<grid, 256, 0, stream>>>(x0, wsf, g1b, g2b, convb, outp);
}

// Round 19
// 124.159 us; speedup vs baseline: 14.6449x; 14.6449x over previous
//
#include <hip/hip_runtime.h>
#include <math.h>

#define Bx 16
#define Cx 64
#define Hx 128
#define Wx 128
#define HWx (Hx * Wx)

#define TW 32
#define TH 8
#define CCH 8
#define HALO_W (TW + 2)
#define HALO_H (TH + 2)
#define CPLANE (HALO_H * HALO_W)          // 340
#define CHUNK_ELEMS (CCH * CPLANE)        // 2720
#define NCHUNK (Cx / CCH)                 // 8

// workspace layout (float/u32 offsets) — R13/R17 layout (gpack8)
#define WS_CWB   0                         // 1x1 B-fragments bf16: 2048 u32
#define WS_GPACK 2048                      // gpack8[c*72 + k*8 + rg]  4608  (rg=r*2+g)
#define WS_KERN  6656                      // per-b [c*36+k*4+g]       16*2304
#define WS_ATT   43520                     // per-b [c*4+r]            16*256

typedef short bf16x8 __attribute__((ext_vector_type(8)));
typedef float f32x4  __attribute__((ext_vector_type(4)));
typedef float f32x2  __attribute__((ext_vector_type(2)));
typedef unsigned int u32x4 __attribute__((ext_vector_type(4)));

__device__ __host__ inline unsigned rne_bf16(float f) {
    union { float f; unsigned u; } v; v.f = f;
    return (v.u + 0x7fffu + ((v.u >> 16) & 1u)) >> 16;
}

// rbuf row swizzle: 4 slots of 16B per 64B pixel row (R13-validated)
#define RSWZ(p) ((((p) & 3) ^ (((p) >> 2) & 3)))

// ---------------- prep: hypernetwork + weight repacking (R17 verbatim) ----------------
__global__ __launch_bounds__(256)
void da_prep(const float* __restrict__ x_deg,
             const float* __restrict__ kw1,
             const float* __restrict__ kw2,
             const float* __restrict__ convw,
             const float* __restrict__ ca_w1,
             const float* __restrict__ ca_w2,
             const float* __restrict__ g1w,
             const float* __restrict__ g2w,
             float* __restrict__ ws)
{
    const int b = blockIdx.x;
    const int tid = threadIdx.x;
    unsigned int* wsu = (unsigned int*)ws;

    if (b == Bx) {
        // 1x1 weights as MFMA B-fragments, bf16 RNE (R12-validated layout).
        for (int i = tid; i < 2048; i += 256) {
            const int t    = i >> 8;
            const int rem  = i & 255;
            const int lane = rem >> 2;
            const int w    = rem & 3;
            const int nt = t >> 1, ks = t & 1;
            const int o = nt * 16 + (lane & 15);
            const int c = ks * 32 + ((lane >> 4) << 3) + w * 2;
            const unsigned lo = rne_bf16(convw[o * 64 + c]);
            const unsigned hi = rne_bf16(convw[o * 64 + c + 1]);
            wsu[WS_CWB + i] = lo | (hi << 16);
        }
        // guide weights packed [c][k][8rg]: rg adjacent -> float2 pairs
        for (int i = tid; i < 4608; i += 256) {
            const int c = i / 72;
            const int rem = i - c * 72;
            const int k  = rem >> 3;
            const int rg = rem & 7;
            const int r = rg >> 1;
            const int g = rg & 1;
            const float* src = g ? g2w : g1w;
            ws[WS_GPACK + i] = src[(r * Cx + c) * 9 + k];
        }
        return;
    }

    __shared__ float h1[16];
    __shared__ float a1[16];
    if (tid < 32) {
        const int j = tid & 15;
        const float* wsrc = (tid < 16) ? (kw1 + j * Cx) : (ca_w1 + j * Cx);
        float acc = 0.f;
        #pragma unroll 8
        for (int c = 0; c < Cx; ++c) acc = fmaf(x_deg[b * Cx + c], wsrc[c], acc);
        acc = acc > 0.f ? acc : 0.1f * acc;               // leaky_relu 0.1
        if (tid < 16) h1[j] = acc; else a1[j] = acc;
    }
    __syncthreads();

    for (int o4 = tid; o4 < 4 * 576; o4 += 256) {
        const int g = o4 / 576;
        const int o = o4 - g * 576;
        float acc = 0.f;
        #pragma unroll
        for (int i = 0; i < 4; ++i)
            acc = fmaf(h1[g * 4 + i], kw2[(g * 576 + o) * 4 + i], acc);
        const int c = o / 9;
        const int k = o - c * 9;
        ws[WS_KERN + b * 2304 + c * 36 + k * 4 + g] = acc;
    }
    {
        const int r = tid >> 6;
        const int c = tid & 63;
        float acc = 0.f;
        #pragma unroll
        for (int i = 0; i < 4; ++i)
            acc = fmaf(a1[r * 4 + i], ca_w2[(r * Cx + c) * 4 + i], acc);
        ws[WS_ATT + b * 256 + c * 4 + r] = 1.f / (1.f + expf(-acc));
    }
}

// ---------------- main: R17 verbatim, __launch_bounds__(256,3) ----------------
// R18 closed the book on pipelining: even a ga[8]-only overlap spills.
// R17 (126us clean): 88 VGPR + 64 AGPR = 152/wave, LDS 46KB -> both budgets
// permit 3 waves/SIMD, but (256,2) lets the allocator relax to the 2-wave
// budget. This round: (256,3) asks for the 170-reg budget. R17's body (88)
// should fit where R13's (~96+) did not. Tripwire: WRITE must stay exactly
// 65536 KB; if it balloons, revert to R17 permanently.
__global__ __launch_bounds__(256, 3)
void da_main(const float* __restrict__ x0,
             const float* __restrict__ ws,
             const float* __restrict__ g1b,
             const float* __restrict__ g2b,
             const float* __restrict__ convb,
             float* __restrict__ out)
{
    const int b  = blockIdx.z;
    const int h0 = blockIdx.y * TH;
    const int w0 = blockIdx.x * TW;
    const int tid = threadIdx.x;
    const int tx = tid & (TW - 1);
    const int ty = tid >> 5;
    const int lane = tid & 63;
    const int wave = tid >> 6;

    // swts: pass1 = gpack8 [c][k][8] (4608 fl); pass2 = skern[0,2304)+satt[2304,2560)
    __shared__ __align__(16) float swts[4608];            // 18,432 B
    // pool: sx float[2720] @0 | rbuf [wave][64pix][32ch] bf16 @10880 (16 KB)
    // after GEMM: pool dead -> sy transpose (4 x 1088 fl)
    __shared__ __align__(16) char pool[27264];
    float* sx = (float*)pool;
    char*  rbuf = pool + 10880;
    // total 46,080 B -> 3 blocks/CU by LDS

    const float* xb  = x0 + (size_t)b * Cx * HWx;
    const float* kws = ws + WS_KERN + b * 2304;
    const float* aws = ws + WS_ATT  + b * 256;
    const unsigned int* wsu = (const unsigned int*)ws;

    // --- per-thread staging offsets, computed ONCE (named ints, no array) ---
    int o0, o1, o2, o3, o4, o5, o6, o7, o8, o9, o10;
    unsigned vmask = 0u;
#define MKOFF(i, oname)                                                        \
    do {                                                                       \
        const int e   = tid + (i) * 256;                                       \
        const int cc  = e / CPLANE;                                            \
        const int rem = e - cc * CPLANE;                                       \
        const int row = rem / HALO_W;                                          \
        const int col = rem - row * HALO_W;                                    \
        const int gh  = h0 - 1 + row;                                          \
        const int gw  = w0 - 1 + col;                                          \
        oname = cc * HWx + gh * Wx + gw;                                       \
        if (e < CHUNK_ELEMS && (unsigned)gh < Hx && (unsigned)gw < Wx)         \
            vmask |= (1u << (i));                                              \
    } while (0)
    MKOFF(0, o0);  MKOFF(1, o1);  MKOFF(2, o2);  MKOFF(3, o3);
    MKOFF(4, o4);  MKOFF(5, o5);  MKOFF(6, o6);  MKOFF(7, o7);
    MKOFF(8, o8);  MKOFF(9, o9);  MKOFF(10, o10);
#undef MKOFF

    // batched staging: issue all loads, then all LDS writes (R10-proven)
#define STAGE_CHUNK(ch)                                                        \
    do {                                                                       \
        const float* src = xb + (size_t)(ch) * CCH * HWx;                      \
        float v0 = 0.f, v1 = 0.f, v2 = 0.f, v3 = 0.f, v4 = 0.f, v5 = 0.f;     \
        float v6 = 0.f, v7 = 0.f, v8 = 0.f, v9 = 0.f, v10 = 0.f;              \
        if (vmask & 1u)      v0  = src[o0];                                    \
        if (vmask & 2u)      v1  = src[o1];                                    \
        if (vmask & 4u)      v2  = src[o2];                                    \
        if (vmask & 8u)      v3  = src[o3];                                    \
        if (vmask & 16u)     v4  = src[o4];                                    \
        if (vmask & 32u)     v5  = src[o5];                                    \
        if (vmask & 64u)     v6  = src[o6];                                    \
        if (vmask & 128u)    v7  = src[o7];                                    \
        if (vmask & 256u)    v8  = src[o8];                                    \
        if (vmask & 512u)    v9  = src[o9];                                    \
        if (vmask & 1024u)   v10 = src[o10];                                   \
        sx[tid]           = v0;   sx[tid + 256]  = v1;                         \
        sx[tid + 512]     = v2;   sx[tid + 768]  = v3;                         \
        sx[tid + 1024]    = v4;   sx[tid + 1280] = v5;                         \
        sx[tid + 1536]    = v6;   sx[tid + 1792] = v7;                         \
        sx[tid + 2048]    = v8;   sx[tid + 2304] = v9;                         \
        if (tid < CHUNK_ELEMS - 2560) sx[tid + 2560] = v10;                    \
    } while (0)

    // --- prologue: gpack8 (1152 float4) batched into LDS (R13-validated) ---
    {
        const float4* s4 = (const float4*)(ws + WS_GPACK);
        float4* d4 = (float4*)swts;
        const float4 g0 = s4[tid], g1 = s4[tid + 256];
        const float4 g2 = s4[tid + 512], g3 = s4[tid + 768];
        float4 g4 = (float4){0.f, 0.f, 0.f, 0.f};
        if (tid < 128) g4 = s4[tid + 1024];
        d4[tid] = g0; d4[tid + 256] = g1; d4[tid + 512] = g2; d4[tid + 768] = g3;
        if (tid < 128) d4[tid + 1024] = g4;
    }

    // ================= PASS 1: guide convs -> argmax (packed FMA) =================
    float ga[8];
    #pragma unroll
    for (int r = 0; r < 4; ++r) { ga[r] = g1b[r]; ga[4 + r] = g2b[r]; }

    #pragma unroll 1
    for (int ch = 0; ch < NCHUNK; ++ch) {
        __syncthreads();
        STAGE_CHUNK(ch);
        __syncthreads();

        float pg[8] = {0.f, 0.f, 0.f, 0.f, 0.f, 0.f, 0.f, 0.f};
        #pragma unroll
        for (int cc = 0; cc < CCH; ++cc) {
            const int c = ch * CCH + cc;
            float n[9];
            #pragma unroll
            for (int kh = 0; kh < 3; ++kh)
                #pragma unroll
                for (int kw = 0; kw < 3; ++kw)
                    n[kh * 3 + kw] = sx[cc * CPLANE + (ty + kh) * HALO_W + (tx + kw)];
            const float4* wp = (const float4*)(swts + c * 72);
            // packed pairs (rg0,rg1)(rg2,rg3)(rg4,rg5)(rg6,rg7); per-component
            // chains k-ascending — bit-identical to R17 (argmax-safe).
            f32x2 a0 = {0.f, 0.f}, a1 = {0.f, 0.f}, a2 = {0.f, 0.f}, a3 = {0.f, 0.f};
            #pragma unroll
            for (int k = 0; k < 9; ++k) {
                const float4 q0 = wp[k * 2];
                const float4 q1 = wp[k * 2 + 1];
                const f32x2 nn = {n[k], n[k]};
                a0 = __builtin_elementwise_fma(nn, (f32x2){q0.x, q0.y}, a0);
                a1 = __builtin_elementwise_fma(nn, (f32x2){q0.z, q0.w}, a1);
                a2 = __builtin_elementwise_fma(nn, (f32x2){q1.x, q1.y}, a2);
                a3 = __builtin_elementwise_fma(nn, (f32x2){q1.z, q1.w}, a3);
            }
            // rg = r*2+g -> pg index r + g*4
            pg[0] += a0.x; pg[4] += a0.y;
            pg[1] += a1.x; pg[5] += a1.y;
            pg[2] += a2.x; pg[6] += a2.y;
            pg[3] += a3.x; pg[7] += a3.y;
        }
        #pragma unroll
        for (int i = 0; i < 8; ++i) ga[i] += pg[i];
    }

    int r1 = 0, r2 = 0;
    {
        float m = ga[0];
        #pragma unroll
        for (int r = 1; r < 4; ++r) if (ga[r] > m) { m = ga[r]; r1 = r; }   // first-max ties
        float m2 = ga[4];
        #pragma unroll
        for (int r = 1; r < 4; ++r) if (ga[4 + r] > m2) { m2 = ga[4 + r]; r2 = r; }
    }

    // --- pass transition: overlay skern+satt into swts (batched, R12) ---
    __syncthreads();
    {
        const float4* k4 = (const float4*)kws;
        const float4 k0 = k4[tid], k1 = k4[tid + 256];
        const float kt = kws[2048 + tid];
        const float at = aws[tid];
        float4* kd4 = (float4*)swts;                  // skern at 0
        kd4[tid] = k0; kd4[tid + 256] = k1;
        swts[2048 + tid] = kt;                        // skern tail
        swts[2304 + tid] = at;                        // satt
    }
    // visibility: pass-2 loop-top barrier

    // ================= PASS 2: depthwise -> bf16 rbuf, K-split GEMM (R15) =================
#define DW_CHUNK(ch)                                                           \
    do {                                                                       \
        unsigned int us[4] = {0u, 0u, 0u, 0u};                                 \
        _Pragma("unroll")                                                      \
        for (int cc = 0; cc < CCH; ++cc) {                                     \
            const int c = (ch) * CCH + cc;                                     \
            float n[9];                                                        \
            _Pragma("unroll")                                                  \
            for (int kh = 0; kh < 3; ++kh)                                     \
                _Pragma("unroll")                                              \
                for (int kw = 0; kw < 3; ++kw)                                 \
                    n[kh * 3 + kw] = sx[cc * CPLANE + (ty + kh) * HALO_W + (tx + kw)]; \
            float dw = 0.f;                                                    \
            _Pragma("unroll")                                                  \
            for (int k = 0; k < 9; ++k)                                        \
                dw = fmaf(n[k], swts[c * 36 + k * 4 + r1], dw);                \
            const float routed = dw > 0.f ? dw : 0.1f * dw;                    \
            us[cc >> 1] |= rne_bf16(routed) << ((cc & 1) * 16);                \
        }                                                                      \
        const int byteoff = wave * 4096 + lane * 64 +                          \
                            ((((ch) & 3) ^ RSWZ(lane)) << 4);                  \
        *(u32x4*)(rbuf + byteoff) = (u32x4){us[0], us[1], us[2], us[3]};       \
    } while (0)

    f32x4 acc[4][4];

#define GEMM_HALF(ks)                                                          \
    do {                                                                       \
        const bf16x8* bglob = (const bf16x8*)(wsu + WS_CWB);                   \
        bf16x8 av[4];                                                          \
        _Pragma("unroll")                                                      \
        for (int mt = 0; mt < 4; ++mt) {                                       \
            const int pix = mt * 16 + (lane & 15);                             \
            const int sk = lane >> 4;                                          \
            av[mt] = *(const bf16x8*)(rbuf + wave * 4096 + pix * 64 +          \
                                      ((sk ^ RSWZ(pix)) << 4));                \
        }                                                                      \
        bf16x8 bv[4];                                                          \
        _Pragma("unroll")                                                      \
        for (int nt = 0; nt < 4; ++nt)                                         \
            bv[nt] = bglob[(nt * 2 + (ks)) * 64 + lane];                       \
        _Pragma("unroll")                                                      \
        for (int mt = 0; mt < 4; ++mt)                                         \
            _Pragma("unroll")                                                  \
            for (int nt = 0; nt < 4; ++nt)                                     \
                acc[mt][nt] = __builtin_amdgcn_mfma_f32_16x16x32_bf16(         \
                    av[mt], bv[nt], acc[mt][nt], 0, 0, 0);                     \
    } while (0)

    #pragma unroll 1
    for (int ch = 0; ch < 4; ++ch) {
        __syncthreads();
        STAGE_CHUNK(ch);
        __syncthreads();
        DW_CHUNK(ch);
    }
    #pragma unroll
    for (int mt = 0; mt < 4; ++mt)
        #pragma unroll
        for (int nt = 0; nt < 4; ++nt)
            acc[mt][nt] = (f32x4){0.f, 0.f, 0.f, 0.f};
    GEMM_HALF(0);          // same-wave rbuf write->read: in-order DS

    #pragma unroll 1
    for (int ch = 4; ch < 8; ++ch) {
        __syncthreads();
        STAGE_CHUNK(ch);
        __syncthreads();
        DW_CHUNK(ch);
    }
    GEMM_HALF(1);

    __syncthreads();       // all sx/rbuf reads done: pool becomes sy

    // --- epilogue per nt-group: padded transpose + store (R13-validated) ---
    const int hh = h0 + ty;
    const int ww = w0 + tx;
    float* op = out + (size_t)b * Cx * HWx + hh * Wx + ww;
    const float* xp = xb + hh * Wx + ww;
    float* syw = (float*)pool + wave * 1088;
    #pragma unroll
    for (int nt = 0; nt < 4; ++nt) {
        #pragma unroll
        for (int mt = 0; mt < 4; ++mt)
            #pragma unroll
            for (int q = 0; q < 4; ++q)
                syw[(mt * 16 + (lane >> 4) * 4 + q) * 17 + (lane & 15)] = acc[mt][nt][q];
        #pragma unroll
        for (int t = 0; t < 16; ++t) {
            const int o = nt * 16 + t;
            const float v = syw[lane * 17 + t] + convb[o]
                          + xp[(size_t)o * HWx] * swts[2304 + o * 4 + r2];
            op[(size_t)o * HWx] = v;
        }
    }
}

extern "C" void kernel_launch(void* const* d_in, const int* in_sizes, int n_in,
                              void* d_out, int out_size, void* d_ws, size_t ws_size,
                              hipStream_t stream) {
    const float* x0     = (const float*)d_in[0];
    const float* x_deg  = (const float*)d_in[1];
    const float* kw1    = (const float*)d_in[2];
    const float* kw2    = (const float*)d_in[3];
    const float* convw  = (const float*)d_in[4];
    const float* convb  = (const float*)d_in[5];
    const float* ca_w1  = (const float*)d_in[6];
    const float* ca_w2  = (const float*)d_in[7];
    const float* g1w    = (const float*)d_in[8];
    const float* g1b    = (const float*)d_in[9];
    const float* g2w    = (const float*)d_in[10];
    const float* g2b    = (const float*)d_in[11];
    float* outp = (float*)d_out;
    float* wsf  = (float*)d_ws;

    da_prep<<<Bx + 1, 256, 0, stream>>>(x_deg, kw1, kw2, convw, ca_w1, ca_w2,
                                        g1w, g2w, wsf);

    dim3 grid(Wx / TW, Hx / TH, Bx);   // 4 x 16 x 16 = 1024 blocks
    da_main<<<grid, 256, 0, stream>>>(x0, wsf, g1b, g2b, convb, outp);
}